// Round 1
// baseline (940.941 us; speedup 1.0000x reference)
//
#include <hip/hip_runtime.h>

typedef _Float16 f16;
typedef _Float16 f16x8 __attribute__((ext_vector_type(8)));
typedef float f32x4 __attribute__((ext_vector_type(4)));

__device__ __forceinline__ void async_cp16(const void* g, void* l) {
  __builtin_amdgcn_global_load_lds(
      (const __attribute__((address_space(1))) void*)g,
      (__attribute__((address_space(3))) void*)l, 16, 0, 0);
}

#define BARRIER()               \
  __builtin_amdgcn_s_barrier(); \
  __builtin_amdgcn_sched_barrier(0)

// C = A @ Bt^T, A [M][K] f16, Bt [N][K] f16. 256x256 tile, BK=64, 8 waves
// (2M x 4N), per-wave 128x64 via 8x4 16x16x32 MFMA frags.
// 8-phase counted-vmcnt schedule (T2+T3+T4+T5):
//   LDS [2buf][2 k-half(32)][256 rows][32 k] per operand = 128 KiB total.
//   Per K-tile, 4 phases (ks,nh): {ds_read frags | stage 1 half-tile ->
//   raw barrier -> setprio(1) 16 MFMA setprio(0) -> barrier}.
//   Stage slots: P0: B-ks1(t+1) / P1: A-ks0(t+2) / P2: B-ks0(t+2) /
//   P3: A-ks1(t+2) -- each lands >=1 barrier after its region's last read.
//   vmcnt(6) once per K-tile at P3 (3 half-tiles = 6 loads stay in flight);
//   never vmcnt(0) except the drain at t = nT-2.
// Swizzle: LDS 16B-unit u holds k-group u^(row&3) (pre-swizzled global src,
// linear gload_lds dest; reads use swz = (lane>>4)^(lane&3)) -> 2-way banks.
template <int EPI>
__global__ __launch_bounds__(512, 2) void gemm256(
    const f16* __restrict__ A, const f16* __restrict__ Bt,
    const float* __restrict__ bias, f16* __restrict__ C,
    int M, int N, int K) {
  __shared__ alignas(16) f16 sA[2][2][256][32];
  __shared__ alignas(16) f16 sB[2][2][256][32];
  const int tid = threadIdx.x;
  const int lane = tid & 63;
  const int wave = tid >> 6;
  const int wm = (wave >> 2) * 128;  // wave's 128-row band
  const int wn = (wave & 3) * 64;    // wave's 64-col band
  const int l15 = lane & 15;
  const int swz = (((lane >> 4) ^ (lane & 3)) << 3);  // element offset of 8-grp

  // XCD-aware remap: XCD x owns mt in [x*32, x*32+32), all 4 nt -> A-panel
  // (512 KB) + full B (2 MB) resident in that XCD's L2.
  int mt, nt;
  if (gridDim.x == 4 && gridDim.y == 256) {
    const int id = blockIdx.y * 4 + blockIdx.x;  // [0,1024)
    const int j = id >> 3;                       // [0,128)
    mt = (id & 7) * 32 + (j >> 2);
    nt = j & 3;
  } else {
    nt = blockIdx.x;
    mt = blockIdx.y;
  }
  const long long bm = (long long)mt * 256;
  const long long bn = (long long)nt * 256;
  const f16* const Abase = A + bm * (long long)K;
  const f16* const Bbase = Bt + bn * (long long)K;

  // Staging: load i of this wave fills LDS 16B-units [(wave*2+i)*64, +64)
  // of one [256][32] half-tile region; global source is inverse-swizzled.
  int gOff[2];
#pragma unroll
  for (int i = 0; i < 2; ++i) {
    const int cu = (wave * 2 + i) * 64 + lane;
    const int row = cu >> 2;
    gOff[i] = row * K + (((cu & 3) ^ (row & 3)) << 3);
  }
  auto stage = [&](const f16* gbase, f16* lbase, int k0) {
#pragma unroll
    for (int i = 0; i < 2; ++i)
      async_cp16(gbase + gOff[i] + k0, lbase + (wave * 2 + i) * 512);
  };

  f32x4 acc[8][4] = {};
  const int nT = K >> 6;

#define READ_A(KS)                            \
  _Pragma("unroll") for (int m = 0; m < 8; ++m) \
      af[m] = *(const f16x8*)&sA[cur][KS][wm + m * 16 + l15][swz];
#define READ_B(KS, NH)                        \
  _Pragma("unroll") for (int n = 0; n < 2; ++n) \
      bf[n] = *(const f16x8*)&sB[cur][KS][wn + (NH) * 32 + n * 16 + l15][swz];
#define PHASE_MFMA(NH)                                                 \
  __builtin_amdgcn_s_setprio(1);                                       \
  _Pragma("unroll") for (int m = 0; m < 8; ++m)                        \
      _Pragma("unroll") for (int n = 0; n < 2; ++n)                    \
          acc[m][(NH) * 2 + n] = __builtin_amdgcn_mfma_f32_16x16x32_f16( \
              af[m], bf[n], acc[m][(NH) * 2 + n], 0, 0, 0);            \
  __builtin_amdgcn_s_setprio(0)

  // Prologue: tile0 (A0,A1,B0,B1) + tile1 (A0,B0,A1); vmcnt(6) retires the
  // 8 oldest (= tile0), leaving tile1's 3 half-tiles (6 loads) in flight.
  stage(Abase, &sA[0][0][0][0], 0);
  stage(Abase, &sA[0][1][0][0], 32);
  stage(Bbase, &sB[0][0][0][0], 0);
  stage(Bbase, &sB[0][1][0][0], 32);
  stage(Abase, &sA[1][0][0][0], 64);
  stage(Bbase, &sB[1][0][0][0], 64);
  stage(Abase, &sA[1][1][0][0], 96);
  asm volatile("s_waitcnt vmcnt(6)" ::: "memory");
  BARRIER();

  for (int t = 0; t < nT; ++t) {
    const int cur = t & 1;
    const int nxt = cur ^ 1;
    f16x8 af[8], bf[2];
    // ---- P0: ks=0, nh=0
    READ_A(0);
    READ_B(0, 0);
    if (t + 1 < nT) stage(Bbase, &sB[nxt][1][0][0], (t + 1) * 64 + 32);
    BARRIER();
    PHASE_MFMA(0);
    BARRIER();
    // ---- P1: ks=0, nh=1 (af reused)
    READ_B(0, 1);
    if (t + 2 < nT) stage(Abase, &sA[cur][0][0][0], (t + 2) * 64);
    BARRIER();
    PHASE_MFMA(1);
    BARRIER();
    // ---- P2: ks=1, nh=0
    READ_A(1);
    READ_B(1, 0);
    if (t + 2 < nT) stage(Bbase, &sB[cur][0][0][0], (t + 2) * 64);
    BARRIER();
    PHASE_MFMA(0);
    BARRIER();
    // ---- P3: ks=1, nh=1 (af reused)
    READ_B(1, 1);
    if (t + 2 < nT) stage(Abase, &sA[cur][1][0][0], (t + 2) * 64 + 32);
    BARRIER();
    PHASE_MFMA(1);
    if (t + 2 < nT)
      asm volatile("s_waitcnt vmcnt(6)" ::: "memory");
    else if (t + 2 == nT)
      asm volatile("s_waitcnt vmcnt(0)" ::: "memory");
    BARRIER();
  }
#undef READ_A
#undef READ_B
#undef PHASE_MFMA

  // Epilogue. 16x16 C/D: col = lane&15, row = (lane>>4)*4 + reg.
#pragma unroll
  for (int n = 0; n < 4; ++n) {
    const long long col = bn + wn + n * 16 + l15;
    float bval = 0.f;
    if (EPI == 0) bval = bias[col];
#pragma unroll
    for (int m = 0; m < 8; ++m) {
      const long long rowb = bm + wm + m * 16 + (lane >> 4) * 4;
#pragma unroll
      for (int r = 0; r < 4; ++r) {
        float v = acc[m][n][r];
        if (EPI == 0) v = fmaxf(v + bval, 0.f);
        C[(rowb + r) * N + col] = (f16)v;
      }
    }
  }
}

// One wave per row: LayerNorm(y) * g + b, relu, write f16. (R2-proven.)
__global__ __launch_bounds__(256) void ln_relu_kernel(
    const f16* __restrict__ Y, const float* __restrict__ g,
    const float* __restrict__ b, f16* __restrict__ H) {
  const int lane = threadIdx.x & 63;
  const int wave = threadIdx.x >> 6;
  const long long row = (long long)blockIdx.x * 4 + wave;
  const f16* y = Y + row * 1024;
  float x[16];
  float s1 = 0.f, s2 = 0.f;
#pragma unroll
  for (int p = 0; p < 2; ++p) {
    f16x8 v = *(const f16x8*)(y + p * 512 + lane * 8);
#pragma unroll
    for (int e = 0; e < 8; ++e) {
      const float f = (float)v[e];
      x[p * 8 + e] = f;
      s1 += f;
      s2 += f * f;
    }
  }
#pragma unroll
  for (int off = 32; off >= 1; off >>= 1) {
    s1 += __shfl_xor(s1, off);
    s2 += __shfl_xor(s2, off);
  }
  const float mean = s1 * (1.f / 1024.f);
  const float var = fmaxf(s2 * (1.f / 1024.f) - mean * mean, 0.f);
  const float inv = rsqrtf(var + 1e-6f);
  f16* h = H + row * 1024;
#pragma unroll
  for (int p = 0; p < 2; ++p) {
    f16x8 o;
#pragma unroll
    for (int e = 0; e < 8; ++e) {
      const int c = p * 512 + lane * 8 + e;
      const float v = (x[p * 8 + e] - mean) * inv * g[c] + b[c];
      o[e] = (f16)fmaxf(v, 0.f);
    }
    *(f16x8*)(h + p * 512 + lane * 8) = o;
  }
}

// Fused layer-3 LN + relu + output dot (R2-proven):
// out[row] = relu(dot(relu(LN(y)*g+b), Wout) + bout)
__global__ __launch_bounds__(256) void ln_relu_out_kernel(
    const f16* __restrict__ Y, const float* __restrict__ g,
    const float* __restrict__ b, const float* __restrict__ Wout,
    const float* __restrict__ bout, float* __restrict__ out) {
  const int lane = threadIdx.x & 63;
  const int wave = threadIdx.x >> 6;
  const long long row = (long long)blockIdx.x * 4 + wave;
  const f16* y = Y + row * 1024;
  float x[16];
  float s1 = 0.f, s2 = 0.f;
#pragma unroll
  for (int p = 0; p < 2; ++p) {
    f16x8 v = *(const f16x8*)(y + p * 512 + lane * 8);
#pragma unroll
    for (int e = 0; e < 8; ++e) {
      const float f = (float)v[e];
      x[p * 8 + e] = f;
      s1 += f;
      s2 += f * f;
    }
  }
#pragma unroll
  for (int off = 32; off >= 1; off >>= 1) {
    s1 += __shfl_xor(s1, off);
    s2 += __shfl_xor(s2, off);
  }
  const float mean = s1 * (1.f / 1024.f);
  const float var = fmaxf(s2 * (1.f / 1024.f) - mean * mean, 0.f);
  const float inv = rsqrtf(var + 1e-6f);
  float dot = 0.f;
#pragma unroll
  for (int p = 0; p < 2; ++p) {
#pragma unroll
    for (int e = 0; e < 8; ++e) {
      const int c = p * 512 + lane * 8 + e;
      const float v = fmaxf((x[p * 8 + e] - mean) * inv * g[c] + b[c], 0.f);
      dot += v * Wout[c];
    }
  }
#pragma unroll
  for (int off = 32; off >= 1; off >>= 1) dot += __shfl_xor(dot, off);
  if (lane == 0) out[row] = fmaxf(dot + bout[0], 0.f);
}

// fp32 -> f16 elementwise (8 per thread)
__global__ __launch_bounds__(256) void cvt_f16_kernel(const float* __restrict__ X,
                                                      f16* __restrict__ Y,
                                                      long long n) {
  const long long i = ((long long)blockIdx.x * 256 + threadIdx.x) * 8;
  if (i >= n) return;
  const float4* X4 = (const float4*)(X + i);
  const float4 a = X4[0], c = X4[1];
  f16x8 o;
  o[0] = (f16)a.x; o[1] = (f16)a.y; o[2] = (f16)a.z; o[3] = (f16)a.w;
  o[4] = (f16)c.x; o[5] = (f16)c.y; o[6] = (f16)c.z; o[7] = (f16)c.w;
  *(f16x8*)(Y + i) = o;
}

// W [K][N] fp32 -> Wt [N][K] f16, 64x64 LDS tiles
__global__ __launch_bounds__(256) void transpose_cvt(const float* __restrict__ W,
                                                     f16* __restrict__ Wt, int K,
                                                     int N) {
  __shared__ float tile[64][65];
  const int bn = blockIdx.x * 64;
  const int bk = blockIdx.y * 64;
  const int tx = threadIdx.x & 63;
  const int ty = threadIdx.x >> 6;  // 0..3
#pragma unroll
  for (int i = 0; i < 64; i += 4)
    tile[ty + i][tx] = W[(long long)(bk + ty + i) * N + bn + tx];
  __syncthreads();
#pragma unroll
  for (int i = 0; i < 64; i += 4)
    Wt[(long long)(bn + ty + i) * K + bk + tx] = (f16)tile[tx][ty + i];
}

extern "C" void kernel_launch(void* const* d_in, const int* in_sizes, int n_in,
                              void* d_out, int out_size, void* d_ws, size_t ws_size,
                              hipStream_t stream) {
  const float* desc = (const float*)d_in[0];
  const float* W0 = (const float*)d_in[1];
  const float* b0 = (const float*)d_in[2];
  const float* W1 = (const float*)d_in[3];
  const float* g1 = (const float*)d_in[4];
  const float* be1 = (const float*)d_in[5];
  const float* W2 = (const float*)d_in[6];
  const float* g2 = (const float*)d_in[7];
  const float* be2 = (const float*)d_in[8];
  const float* W3 = (const float*)d_in[9];
  const float* g3 = (const float*)d_in[10];
  const float* be3 = (const float*)d_in[11];
  const float* Wout = (const float*)d_in[12];
  const float* bout = (const float*)d_in[13];
  float* out = (float*)d_out;

  const long long Nrows = 65536, D = 512, W = 1024;
  char* p = (char*)d_ws;
  f16* descH = (f16*)p; p += Nrows * D * sizeof(f16);   // 67.1 MB
  f16* Wt0 = (f16*)p;   p += D * W * sizeof(f16);       // 1 MB
  f16* Wt1 = (f16*)p;   p += W * W * sizeof(f16);       // 2 MB
  f16* Wt2 = (f16*)p;   p += W * W * sizeof(f16);       // 2 MB
  f16* Wt3 = (f16*)p;   p += W * W * sizeof(f16);       // 2 MB
  f16* H = (f16*)p;     p += Nrows * W * sizeof(f16);   // 134.2 MB
  f16* Y = (f16*)p;     p += Nrows * W * sizeof(f16);   // 134.2 MB
  (void)ws_size; (void)in_sizes; (void)n_in; (void)out_size;

  cvt_f16_kernel<<<(int)(Nrows * D / 8 / 256), 256, 0, stream>>>(desc, descH,
                                                                 Nrows * D);
  transpose_cvt<<<dim3(W / 64, D / 64), 256, 0, stream>>>(W0, Wt0, (int)D, (int)W);
  transpose_cvt<<<dim3(W / 64, W / 64), 256, 0, stream>>>(W1, Wt1, (int)W, (int)W);
  transpose_cvt<<<dim3(W / 64, W / 64), 256, 0, stream>>>(W2, Wt2, (int)W, (int)W);
  transpose_cvt<<<dim3(W / 64, W / 64), 256, 0, stream>>>(W3, Wt3, (int)W, (int)W);

  dim3 ggrid(W / 256, Nrows / 256);  // (4, 256)
  gemm256<0><<<ggrid, 512, 0, stream>>>(descH, Wt0, b0, H, (int)Nrows, (int)W, (int)D);

  gemm256<1><<<ggrid, 512, 0, stream>>>(H, Wt1, nullptr, Y, (int)Nrows, (int)W, (int)W);
  ln_relu_kernel<<<(int)(Nrows / 4), 256, 0, stream>>>(Y, g1, be1, H);

  gemm256<1><<<ggrid, 512, 0, stream>>>(H, Wt2, nullptr, Y, (int)Nrows, (int)W, (int)W);
  ln_relu_kernel<<<(int)(Nrows / 4), 256, 0, stream>>>(Y, g2, be2, H);

  gemm256<1><<<ggrid, 512, 0, stream>>>(H, Wt3, nullptr, Y, (int)Nrows, (int)W, (int)W);
  ln_relu_out_kernel<<<(int)(Nrows / 4), 256, 0, stream>>>(Y, g3, be3, Wout, bout, out);
}